// Round 12
// baseline (804.476 us; speedup 1.0000x reference)
//
#include <hip/hip_runtime.h>

#define FEAT 128
#define RANGE 12800
#define NSLICE 64

// ---------- hist: src & dst partial histograms in one dispatch, ushort-packed ----------
__global__ __launch_bounds__(256) void hist_kernel(const int* __restrict__ src,
                                                   const int* __restrict__ dst,
                                                   unsigned* __restrict__ partialD,
                                                   unsigned* __restrict__ partialS,
                                                   int E, int NP) {
    __shared__ unsigned hpk[RANGE / 2];
    int per = (NP / RANGE) * NSLICE;
    int b = blockIdx.x;
    int halfsel = b / per;
    int q = b % per;
    int r = q / NSLICE;
    int s = q % NSLICE;
    const int* arr = halfsel ? src : dst;
    unsigned* out = halfsel ? partialS : partialD;
    int v0 = r * RANGE;
    int tid = threadIdx.x;
    for (int i = tid; i < RANGE / 2; i += 256) hpk[i] = 0;
    __syncthreads();
    int e0 = (int)((long long)E * s / NSLICE);
    int e1 = (int)((long long)E * (s + 1) / NSLICE);
    for (int e = e0 + tid; e < e1; e += 256) {
        unsigned d = (unsigned)(arr[e] - v0);
        if (d < RANGE) atomicAdd(&hpk[d >> 1], (d & 1) ? 65536u : 1u);
    }
    __syncthreads();
    size_t wbase = ((size_t)s * NP + v0) >> 1;
    for (int i = tid; i < RANGE / 2; i += 256) out[wbase + i] = hpk[i];
}

// ---------- scan phase 1: per-node slice-sums + norms ----------
__global__ __launch_bounds__(256) void scanp1_kernel(const unsigned short* __restrict__ pD,
                                                     const unsigned short* __restrict__ pS,
                                                     int* __restrict__ blockSums,
                                                     float* __restrict__ ns,
                                                     float* __restrict__ nd,
                                                     int NP, int n) {
    __shared__ int buf[256];
    int tid = threadIdx.x;
    int v = blockIdx.x * 256 + tid;
    int ssum = 0, osum = 0;
    #pragma unroll
    for (int s = 0; s < NSLICE; ++s) {
        ssum += pD[(size_t)s * NP + v];
        osum += pS[(size_t)s * NP + v];
    }
    if (v < n) {
        ns[v] = 1.0f / sqrtf((float)(osum < 1 ? 1 : osum));
        nd[v] = 1.0f / sqrtf((float)(ssum < 1 ? 1 : ssum));
    }
    buf[tid] = ssum;
    __syncthreads();
    #pragma unroll
    for (int off = 1; off < 256; off <<= 1) {
        int t = (tid >= off) ? buf[tid - off] : 0;
        __syncthreads();
        buf[tid] += t;
        __syncthreads();
    }
    if (tid == 255) blockSums[blockIdx.x] = buf[255];
}

// ---------- scan phase 2 ----------
__global__ __launch_bounds__(256) void scanp2_kernel(const int* __restrict__ blockSums,
                                                     int* __restrict__ blockOffs, int nb) {
    __shared__ int buf[256];
    int tid = threadIdx.x;
    int v = (tid < nb) ? blockSums[tid] : 0;
    buf[tid] = v;
    __syncthreads();
    #pragma unroll
    for (int off = 1; off < 256; off <<= 1) {
        int t = (tid >= off) ? buf[tid - off] : 0;
        __syncthreads();
        buf[tid] += t;
        __syncthreads();
    }
    if (tid < nb) blockOffs[tid] = buf[tid] - v;
}

// ---------- scan phase 3: per-(node,slice) cursors + compact offsets ----------
__global__ __launch_bounds__(256) void scanp3_kernel(const unsigned short* __restrict__ pD,
                                                     const int* __restrict__ blockOffs,
                                                     int* __restrict__ cursorV,
                                                     int* __restrict__ offsc,
                                                     int NP, int n) {
    __shared__ int buf[256];
    int tid = threadIdx.x;
    int v = blockIdx.x * 256 + tid;
    int ssum = 0;
    #pragma unroll
    for (int s = 0; s < NSLICE; ++s) ssum += pD[(size_t)s * NP + v];
    buf[tid] = ssum;
    __syncthreads();
    #pragma unroll
    for (int off = 1; off < 256; off <<= 1) {
        int t = (tid >= off) ? buf[tid - off] : 0;
        __syncthreads();
        buf[tid] += t;
        __syncthreads();
    }
    int o = blockOffs[blockIdx.x] + buf[tid] - ssum;
    if (v <= n) offsc[v] = o;
    int* cv = cursorV + (size_t)v * NSLICE;
    #pragma unroll
    for (int s = 0; s < NSLICE; ++s) {
        int val = pD[(size_t)s * NP + v];
        cv[s] = o;
        o += val;
    }
}

// ---------- prescale: xs = in_feat * ns (row-major) ----------
__global__ void prescale_kernel(const float* __restrict__ x, const float* __restrict__ ns,
                                float* __restrict__ xs, int n) {
    int i = blockIdx.x * blockDim.x + threadIdx.x;
    if (i >= n * (FEAT / 4)) return;
    int v = i >> 5;
    float w = ns[v];
    float4 t = ((const float4*)x)[i];
    t.x *= w; t.y *= w; t.z *= w; t.w *= w;
    ((float4*)xs)[i] = t;
}

// ---------- fill: place edges via LDS cursors ----------
__global__ __launch_bounds__(256) void fill_kernel(const int* __restrict__ src,
                                                   const int* __restrict__ dst,
                                                   const int* __restrict__ cursorV,
                                                   int* __restrict__ esrc, int E, int NP) {
    __shared__ int cur[RANGE];
    int b = blockIdx.x;
    int r = b / NSLICE;
    int inner = b % NSLICE;
    int s = ((inner & 7) << 3) | (inner >> 3);
    int v0 = r * RANGE;
    int tid = threadIdx.x;
    for (int i = tid; i < RANGE; i += 256)
        cur[i] = cursorV[(size_t)(v0 + i) * NSLICE + s];
    __syncthreads();
    int e0 = (int)((long long)E * s / NSLICE);
    int e1 = (int)((long long)E * (s + 1) / NSLICE);
    for (int e = e0 + tid; e < e1; e += 256) {
        unsigned dd = (unsigned)(dst[e] - v0);
        if (dd < RANGE) {
            int p = atomicAdd(&cur[dd], 1);
            esrc[p] = src[e];
        }
    }
}

// ---------- aggregation: one wave per node, half-wave float4, 8 rows in flight (R7) ----------
__global__ __launch_bounds__(256) void agg_kernel(const float* __restrict__ x,
                                                  const int* __restrict__ offs,
                                                  const int* __restrict__ esrc,
                                                  const float* __restrict__ nd,
                                                  float* __restrict__ m, int n) {
    int gid = blockIdx.x * blockDim.x + threadIdx.x;
    int v = gid >> 6;
    int lane = threadIdx.x & 63;
    int half = lane >> 5;
    int c = lane & 31;
    if (v >= n) return;
    int s0 = offs[v], s1 = offs[v + 1];
    float4 A0 = make_float4(0.f, 0.f, 0.f, 0.f);
    float4 A1 = make_float4(0.f, 0.f, 0.f, 0.f);
    float4 A2 = make_float4(0.f, 0.f, 0.f, 0.f);
    float4 A3 = make_float4(0.f, 0.f, 0.f, 0.f);
    int j = s0 + half;
    for (; j + 6 < s1; j += 8) {
        int e0 = esrc[j], e1 = esrc[j + 2], e2 = esrc[j + 4], e3 = esrc[j + 6];
        float4 t0 = ((const float4*)(x + (size_t)e0 * FEAT))[c];
        float4 t1 = ((const float4*)(x + (size_t)e1 * FEAT))[c];
        float4 t2 = ((const float4*)(x + (size_t)e2 * FEAT))[c];
        float4 t3 = ((const float4*)(x + (size_t)e3 * FEAT))[c];
        A0.x += t0.x; A0.y += t0.y; A0.z += t0.z; A0.w += t0.w;
        A1.x += t1.x; A1.y += t1.y; A1.z += t1.z; A1.w += t1.w;
        A2.x += t2.x; A2.y += t2.y; A2.z += t2.z; A2.w += t2.w;
        A3.x += t3.x; A3.y += t3.y; A3.z += t3.z; A3.w += t3.w;
    }
    for (; j < s1; j += 2) {
        int e0 = esrc[j];
        float4 t0 = ((const float4*)(x + (size_t)e0 * FEAT))[c];
        A0.x += t0.x; A0.y += t0.y; A0.z += t0.z; A0.w += t0.w;
    }
    A0.x += A1.x + A2.x + A3.x;
    A0.y += A1.y + A2.y + A3.y;
    A0.z += A1.z + A2.z + A3.z;
    A0.w += A1.w + A2.w + A3.w;
    A0.x += __shfl_xor(A0.x, 32);
    A0.y += __shfl_xor(A0.y, 32);
    A0.z += __shfl_xor(A0.z, 32);
    A0.w += __shfl_xor(A0.w, 32);
    if (half == 0) {
        float w = nd[v];
        float4 r;
        r.x = A0.x * w; r.y = A0.y * w; r.z = A0.z * w; r.w = A0.w * w;
        ((float4*)(m + (size_t)v * FEAT))[c] = r;
    }
}

// ---------- GEMM: barrier-free K-loop ----------
// W (128x128, 64 KB) staged in LDS once -> ONE barrier total. Each thread owns
// (row, col-half): streams its m-row through VGPRs with 2-chunk-ahead prefetch,
// 64 FMA per k against broadcast-pair LDS reads. No per-chunk __syncthreads ->
// no vmcnt(0) drain stalls (the R7-R11 ~54us plateau).
template<int MODE>   // 0: relu*ns epilogue   1: last layer (h in-place + threshold)
__global__ __launch_bounds__(256) void gemm_kernel(const float* __restrict__ M,
                                                   const float* __restrict__ W,
                                                   const float* __restrict__ bias,
                                                   const float* __restrict__ nsv,
                                                   float* __restrict__ out,
                                                   float* __restrict__ out2, int n) {
    __shared__ float Ws[FEAT][FEAT];   // byte-identical to W (row-major [k][col])
    int tid = threadIdx.x;
    int cg = tid & 1;                  // column half: cols cg*64 .. cg*64+63
    int rloc = tid >> 1;               // local row 0..127
    int row = blockIdx.x * 128 + rloc;

    // stage whole W: 4096 float4, 16 per thread
    #pragma unroll
    for (int i = 0; i < 16; ++i)
        ((float4*)&Ws[0][0])[tid + i * 256] = ((const float4*)W)[tid + i * 256];

    bool valid = row < n;
    const float* mr = M + (size_t)(valid ? row : 0) * FEAT;

    // prefetch chunks 0 and 1 (each chunk = 8 k = 2 float4) while W staging lands
    float4 mb[3][2];
    mb[0][0] = *(const float4*)(mr + 0);
    mb[0][1] = *(const float4*)(mr + 4);
    mb[1][0] = *(const float4*)(mr + 8);
    mb[1][1] = *(const float4*)(mr + 12);

    __syncthreads();   // the only barrier

    float acc[64];
    #pragma unroll
    for (int j = 0; j < 64; ++j) acc[j] = 0.f;

    int cbase = cg * 64;
    for (int c = 0; c < 16; ++c) {
        int nc = c + 2;
        if (nc < 16) {
            mb[nc % 3][0] = *(const float4*)(mr + nc * 8);
            mb[nc % 3][1] = *(const float4*)(mr + nc * 8 + 4);
        }
        float a[8];
        a[0] = mb[c % 3][0].x; a[1] = mb[c % 3][0].y;
        a[2] = mb[c % 3][0].z; a[3] = mb[c % 3][0].w;
        a[4] = mb[c % 3][1].x; a[5] = mb[c % 3][1].y;
        a[6] = mb[c % 3][1].z; a[7] = mb[c % 3][1].w;
        #pragma unroll
        for (int kk = 0; kk < 8; ++kk) {
            int k = c * 8 + kk;
            const float* wrow = &Ws[k][cbase];
            float4 w0 = *(const float4*)(wrow + 0);
            float4 w1 = *(const float4*)(wrow + 4);
            float4 w2 = *(const float4*)(wrow + 8);
            float4 w3 = *(const float4*)(wrow + 12);
            float av = a[kk];
            #pragma unroll
            for (int q = 0; q < 4; ++q) {
                const float4* wq = (q == 0) ? &w0 : (q == 1) ? &w1 : (q == 2) ? &w2 : &w3;
                acc[q * 4 + 0] = fmaf(av, wq->x, acc[q * 4 + 0]);
                acc[q * 4 + 1] = fmaf(av, wq->y, acc[q * 4 + 1]);
                acc[q * 4 + 2] = fmaf(av, wq->z, acc[q * 4 + 2]);
                acc[q * 4 + 3] = fmaf(av, wq->w, acc[q * 4 + 3]);
            }
            float4 w4 = *(const float4*)(wrow + 16);
            float4 w5 = *(const float4*)(wrow + 20);
            float4 w6 = *(const float4*)(wrow + 24);
            float4 w7 = *(const float4*)(wrow + 28);
            #pragma unroll
            for (int q = 0; q < 4; ++q) {
                const float4* wq = (q == 0) ? &w4 : (q == 1) ? &w5 : (q == 2) ? &w6 : &w7;
                acc[16 + q * 4 + 0] = fmaf(av, wq->x, acc[16 + q * 4 + 0]);
                acc[16 + q * 4 + 1] = fmaf(av, wq->y, acc[16 + q * 4 + 1]);
                acc[16 + q * 4 + 2] = fmaf(av, wq->z, acc[16 + q * 4 + 2]);
                acc[16 + q * 4 + 3] = fmaf(av, wq->w, acc[16 + q * 4 + 3]);
            }
            float4 w8  = *(const float4*)(wrow + 32);
            float4 w9  = *(const float4*)(wrow + 36);
            float4 w10 = *(const float4*)(wrow + 40);
            float4 w11 = *(const float4*)(wrow + 44);
            #pragma unroll
            for (int q = 0; q < 4; ++q) {
                const float4* wq = (q == 0) ? &w8 : (q == 1) ? &w9 : (q == 2) ? &w10 : &w11;
                acc[32 + q * 4 + 0] = fmaf(av, wq->x, acc[32 + q * 4 + 0]);
                acc[32 + q * 4 + 1] = fmaf(av, wq->y, acc[32 + q * 4 + 1]);
                acc[32 + q * 4 + 2] = fmaf(av, wq->z, acc[32 + q * 4 + 2]);
                acc[32 + q * 4 + 3] = fmaf(av, wq->w, acc[32 + q * 4 + 3]);
            }
            float4 w12 = *(const float4*)(wrow + 48);
            float4 w13 = *(const float4*)(wrow + 52);
            float4 w14 = *(const float4*)(wrow + 56);
            float4 w15 = *(const float4*)(wrow + 60);
            #pragma unroll
            for (int q = 0; q < 4; ++q) {
                const float4* wq = (q == 0) ? &w12 : (q == 1) ? &w13 : (q == 2) ? &w14 : &w15;
                acc[48 + q * 4 + 0] = fmaf(av, wq->x, acc[48 + q * 4 + 0]);
                acc[48 + q * 4 + 1] = fmaf(av, wq->y, acc[48 + q * 4 + 1]);
                acc[48 + q * 4 + 2] = fmaf(av, wq->z, acc[48 + q * 4 + 2]);
                acc[48 + q * 4 + 3] = fmaf(av, wq->w, acc[48 + q * 4 + 3]);
            }
        }
    }

    if (!valid) return;
    float sc_ = (MODE == 0) ? nsv[row] : 1.0f;
    float* orow = out + (size_t)row * FEAT + cbase;
    const float* brow = bias + cbase;
    #pragma unroll
    for (int q = 0; q < 16; ++q) {
        float4 bv = *(const float4*)(brow + q * 4);
        float4 v;
        v.x = acc[q * 4 + 0] + bv.x;
        v.y = acc[q * 4 + 1] + bv.y;
        v.z = acc[q * 4 + 2] + bv.z;
        v.w = acc[q * 4 + 3] + bv.w;
        v.x = v.x > 0.f ? v.x : 0.f; v.y = v.y > 0.f ? v.y : 0.f;
        v.z = v.z > 0.f ? v.z : 0.f; v.w = v.w > 0.f ? v.w : 0.f;
        if (MODE == 0) {
            v.x *= sc_; v.y *= sc_; v.z *= sc_; v.w *= sc_;
            *(float4*)(orow + q * 4) = v;
        } else {
            *(float4*)(orow + q * 4) = v;
            float4 cth;
            cth.x = v.x >= 0.5f ? 1.f : 0.f;
            cth.y = v.y >= 0.5f ? 1.f : 0.f;
            cth.z = v.z >= 0.5f ? 1.f : 0.f;
            cth.w = v.w >= 0.5f ? 1.f : 0.f;
            *(float4*)(out2 + (size_t)row * FEAT + cbase + q * 4) = cth;
        }
    }
}

extern "C" void kernel_launch(void* const* d_in, const int* in_sizes, int n_in,
                              void* d_out, int out_size, void* d_ws, size_t ws_size,
                              hipStream_t stream) {
    const float* in_feat = (const float*)d_in[0];
    const int*   src     = (const int*)d_in[1];
    const int*   dst     = (const int*)d_in[2];
    const float* W[5] = {(const float*)d_in[3], (const float*)d_in[5], (const float*)d_in[7],
                         (const float*)d_in[9], (const float*)d_in[11]};
    const float* B[5] = {(const float*)d_in[4], (const float*)d_in[6], (const float*)d_in[8],
                         (const float*)d_in[10], (const float*)d_in[12]};
    const int E = in_sizes[1];
    const int N = in_sizes[0] / FEAT;
    const int NRANGE = (N + RANGE - 1) / RANGE;
    const int NP = NRANGE * RANGE;
    const size_t MTOT = (size_t)NP * NSLICE;

    char* ws = (char*)d_ws;
    size_t off = 0;
    auto alloc = [&](size_t bytes) { size_t o = off; off += (bytes + 255) & ~size_t(255); return o; };
    unsigned* partialD = (unsigned*)(ws + alloc(MTOT * 2));
    size_t    pS_off   = alloc(MTOT * 2);
    unsigned* partialS = (unsigned*)(ws + pS_off);
    int*      esrc     = (int*)(ws + pS_off);          // aliases partialS (dead after scanp1)
    int*      cursorV  = (int*)(ws + alloc(MTOT * 4));
    float*    ns       = (float*)(ws + alloc((size_t)N * 4));
    float*    nd       = (float*)(ws + alloc((size_t)N * 4));
    int*      offsc    = (int*)(ws + alloc((size_t)(N + 1) * 4));
    int*      blockSums = (int*)(ws + alloc(1024));
    int*      blockOffs = (int*)(ws + alloc(1024));

    float* out_h = (float*)d_out;              // m scratch; h5 at the end (in-place gemm5)
    float* out_c = out_h + (size_t)N * FEAT;   // scaled-x chain; threshold at the end

    const int histBlocks = 2 * NRANGE * NSLICE;
    const int scanBlocks = NP / 256;
    hist_kernel<<<histBlocks, 256, 0, stream>>>(src, dst, partialD, partialS, E, NP);
    scanp1_kernel<<<scanBlocks, 256, 0, stream>>>((const unsigned short*)partialD,
                                                  (const unsigned short*)partialS,
                                                  blockSums, ns, nd, NP, N);
    scanp2_kernel<<<1, 256, 0, stream>>>(blockSums, blockOffs, scanBlocks);
    scanp3_kernel<<<scanBlocks, 256, 0, stream>>>((const unsigned short*)partialD,
                                                  blockOffs, cursorV, offsc, NP, N);
    prescale_kernel<<<(N * 32 + 255) / 256, 256, 0, stream>>>(in_feat, ns, out_c, N);
    fill_kernel<<<NRANGE * NSLICE, 256, 0, stream>>>(src, dst, cursorV, esrc, E, NP);

    const int agg_blocks = (int)(((size_t)N * 64 + 255) / 256);
    const int gemm_blocks = (N + 127) / 128;

    for (int l = 0; l < 5; ++l) {
        agg_kernel<<<agg_blocks, 256, 0, stream>>>(out_c, offsc, esrc, nd, out_h, N);
        if (l < 4)
            gemm_kernel<0><<<gemm_blocks, 256, 0, stream>>>(out_h, W[l], B[l], ns, out_c, nullptr, N);
        else
            gemm_kernel<1><<<gemm_blocks, 256, 0, stream>>>(out_h, W[l], B[l], ns, out_h, out_c, N);
    }
}